// Round 9
// baseline (153.875 us; speedup 1.0000x reference)
//
#include <hip/hip_runtime.h>

#define CC 64
#define OO 64
#define HH 128
#define WW 128
#define HW (HH*WW)

#define TH 8            // output tile rows per block
#define TW 8            // output tile cols per block
#define WR 15           // window rows (tile + 3x3 reach + bilinear + offset margin [-2,+3))
#define WC 15           // window cols
#define NP 32           // channel pairs (64 ch)
#define RSTR (NP*WC)    // dwords per window row block = 480
#define WINSZ (WR*RSTR) // 7200 dwords = 28.8 KB

typedef __attribute__((ext_vector_type(8))) _Float16 half8;
typedef __attribute__((ext_vector_type(2))) _Float16 h2;
typedef __attribute__((ext_vector_type(4))) float f32x4;

union U { unsigned u; h2 h; };

// ---------------- weight repack to f16, K-index = kk*64+c ----------------
__global__ __launch_bounds__(256) void repackw_kernel(const float* __restrict__ wt,
                                                      const float* __restrict__ ow,
                                                      _Float16* __restrict__ wb,
                                                      _Float16* __restrict__ owb) {
  int i = blockIdx.x * 256 + threadIdx.x;
  if (i < OO * 576) {
    int o = i / 576, r = i % 576;
    int kk = r >> 6, c = r & 63;
    wb[i] = (_Float16)wt[(o * CC + c) * 9 + kk];
  } else if (i < OO * 576 + 32 * 576) {
    int j = i - OO * 576;
    int oc = j / 576, r = j % 576;
    int kk = r >> 6, c = r & 63;
    owb[j] = (oc < 18) ? (_Float16)ow[(oc * CC + c) * 9 + kk] : (_Float16)0.0f;
  }
}

__device__ __forceinline__ float gs(const float* __restrict__ xb, int ch, int r, int c) {
  return ((unsigned)r < (unsigned)HH && (unsigned)c < (unsigned)WW)
             ? xb[(size_t)ch * HW + r * WW + c] : 0.0f;
}

// ---------------- fused: stage f16 window -> offs GEMM -> deform GEMM ----------------
__global__ __launch_bounds__(256, 4) void fused_deform(const float* __restrict__ x,
                                                       const _Float16* __restrict__ wb,
                                                       const _Float16* __restrict__ owb,
                                                       const float* __restrict__ obias,
                                                       const float* __restrict__ bias,
                                                       float* __restrict__ out) {
  __shared__ __align__(16) unsigned win[WINSZ];   // [r][pair][col] f16-pair dwords, 28.8 KB
  __shared__ __align__(16) float obuf[64 * 20];   // 5.1 KB offsets transpose

  int tid = threadIdx.x;
  int blk0 = blockIdx.x;
  int xcd = blk0 & 7, i = blk0 >> 3;
  int s = xcd * 8 + (i >> 4);            // slab 0..63 = b*16 + ht (8 slabs per XCD)
  int b = s >> 4, ht = s & 15, wtile = i & 15;
  int H0 = ht * TH, W0 = wtile * TW;
  int rlo = H0 - 1, clo = W0 - 1;        // window origin, padded coords

  int wave = tid >> 6, lane = tid & 63, lm = lane & 15, lq = lane >> 4;
  const float* xb = x + (size_t)b * CC * HW;

  // ---- stage window: fp32 x -> f16 channel-pair dwords, layout (r*32+p)*15+c ----
  for (int idx = tid; idx < WINSZ; idx += 256) {
    int c = idx % WC;
    int t = idx / WC;                    // r*32 + p
    int p = t & 31, r = t >> 5;
    int xr = H0 + r - 2, xc = W0 + c - 2;
    unsigned v = 0;
    if ((unsigned)xr < (unsigned)HH && (unsigned)xc < (unsigned)WW) {
      const float* sp = xb + ((size_t)(2 * p)) * HW + xr * WW + xc;
      U u; u.h = (h2){(_Float16)sp[0], (_Float16)sp[HW]};
      v = u.u;
    }
    win[idx] = v;
  }
  __syncthreads();

  int row = 2 * wave + (lm >> 3);        // tile-local pixel coords for lane lm
  int col = lm & 7;
  int h = H0 + row, w = W0 + col;
  int pq = lq * 60;                      // (lq*4 pairs) * 15

  // ---- offs GEMM: 18 offset channels for this wave's 16 px (static taps) ----
  {
    f32x4 oacc[2];
    oacc[0] = (f32x4)0.0f; oacc[1] = (f32x4)0.0f;
#pragma unroll
    for (int kk = 0; kk < 9; ++kk) {
      int kh = kk / 3, kw = kk % 3;
      int base = (row + kh + 1) * RSTR + (col + kw + 1) + pq;
      union { unsigned u[4]; half8 v; } A0, A1;
#pragma unroll
      for (int t = 0; t < 4; ++t) {
        A0.u[t] = win[base + t * 15];
        A1.u[t] = win[base + 240 + t * 15];
      }
#pragma unroll
      for (int nt = 0; nt < 2; ++nt) {
        half8 b0 = *(const half8*)&owb[(size_t)(nt * 16 + lm) * 576 + kk * 64 + lq * 8];
        half8 b1 = *(const half8*)&owb[(size_t)(nt * 16 + lm) * 576 + kk * 64 + 32 + lq * 8];
        oacc[nt] = __builtin_amdgcn_mfma_f32_16x16x32_f16(A0.v, b0, oacc[nt], 0, 0, 0);
        oacc[nt] = __builtin_amdgcn_mfma_f32_16x16x32_f16(A1.v, b1, oacc[nt], 0, 0, 0);
      }
    }
#pragma unroll
    for (int nt = 0; nt < 2; ++nt) {
      int oc = nt * 16 + lm;
      if (oc < 18) {
        float bv = obias[oc];
        int idx = (oc < 9) ? (oc * 2) : ((oc - 9) * 2 + 1);
#pragma unroll
        for (int r2 = 0; r2 < 4; ++r2)
          obuf[(wave * 16 + lq * 4 + r2) * 20 + idx] = oacc[nt][r2] + bv;
      }
    }
  }
  __syncthreads();

  float orow[20];
  {
    const float* orp = &obuf[(wave * 16 + lm) * 20];
#pragma unroll
    for (int q = 0; q < 5; ++q) *(float4*)&orow[q * 4] = *(const float4*)(orp + q * 4);
  }

  f32x4 acc[4];
#pragma unroll
  for (int nt = 0; nt < 4; ++nt) acc[nt] = (f32x4)0.0f;

  // ---- Phase 0: all 9 taps of all lanes inside the staged window? ----
  bool okall = true;
#pragma unroll
  for (int kk = 0; kk < 9; ++kk) {
    int kh = kk / 3, kw = kk % 3;
    float ph = (((float)kh + orow[kk * 2]) + (float)h) + 1.0f;
    float pw = (((float)kw + orow[kk * 2 + 1]) + (float)w) + 1.0f;
    ph = fminf(fmaxf(ph, 0.0f), 129.0f);
    pw = fminf(fmaxf(pw, 0.0f), 129.0f);
    int h0 = (int)floorf(ph), w0 = (int)floorf(pw);
    int wr0 = h0 - rlo, wc0 = w0 - clo;
    okall &= (wr0 >= 0) & (wr0 <= WR - 2) & (wc0 >= 0) & (wc0 <= WC - 2);
  }

  if (__builtin_amdgcn_ballot_w64(okall) == ~0ull) {
    // ---- fast path: per tap, 16 ds_read2-style pair loads + packed-f16 lerp ----
#pragma unroll
    for (int kk = 0; kk < 9; ++kk) {
      int kh = kk / 3, kw = kk % 3;
      float ph = (((float)kh + orow[kk * 2]) + (float)h) + 1.0f;
      float pw = (((float)kw + orow[kk * 2 + 1]) + (float)w) + 1.0f;
      ph = fminf(fmaxf(ph, 0.0f), 129.0f);
      pw = fminf(fmaxf(pw, 0.0f), 129.0f);
      float fh0 = floorf(ph), fw0 = floorf(pw);
      int h0 = (int)fh0, w0 = (int)fw0;
      float wh1 = ph - fh0, ww1 = pw - fw0;
      float wh0 = 1.0f - wh1, ww0 = 1.0f - ww1;
      h2 ww0h = {(_Float16)ww0, (_Float16)ww0};
      h2 ww1h = {(_Float16)ww1, (_Float16)ww1};
      h2 wh0h = {(_Float16)wh0, (_Float16)wh0};
      h2 wh1h = {(_Float16)wh1, (_Float16)wh1};
      int b0 = (h0 - rlo) * RSTR + (w0 - clo) + pq;

      union { unsigned u[4]; half8 v; } Af[2];
#pragma unroll
      for (int sh = 0; sh < 2; ++sh) {
        int bs = b0 + sh * 240;
#pragma unroll
        for (int t = 0; t < 4; ++t) {
          U q00, q01, q10, q11;
          q00.u = win[bs + t * 15];
          q01.u = win[bs + t * 15 + 1];
          q10.u = win[bs + RSTR + t * 15];
          q11.u = win[bs + RSTR + t * 15 + 1];
          h2 m1 = q00.h * ww0h + q01.h * ww1h;
          h2 m2 = q10.h * ww0h + q11.h * ww1h;
          h2 vv = m1 * wh0h + m2 * wh1h;
          U o; o.h = vv;
          Af[sh].u[t] = o.u;
        }
      }
#pragma unroll
      for (int nt = 0; nt < 4; ++nt) {
        half8 b0f = *(const half8*)&wb[(size_t)(nt * 16 + lm) * 576 + kk * 64 + lq * 8];
        half8 b1f = *(const half8*)&wb[(size_t)(nt * 16 + lm) * 576 + kk * 64 + 32 + lq * 8];
        acc[nt] = __builtin_amdgcn_mfma_f32_16x16x32_f16(Af[0].v, b0f, acc[nt], 0, 0, 0);
        acc[nt] = __builtin_amdgcn_mfma_f32_16x16x32_f16(Af[1].v, b1f, acc[nt], 0, 0, 0);
      }
    }
  } else {
    // ---- cold exact path (not taken for this data): fp32 gather from x with guards ----
#pragma unroll 1
    for (int kk = 0; kk < 9; ++kk) {
      int kh = kk / 3, kw = kk % 3;
      float ph = (((float)kh + orow[kk * 2]) + (float)h) + 1.0f;
      float pw = (((float)kw + orow[kk * 2 + 1]) + (float)w) + 1.0f;
      ph = fminf(fmaxf(ph, 0.0f), 129.0f);
      pw = fminf(fmaxf(pw, 0.0f), 129.0f);
      float fh0 = floorf(ph), fw0 = floorf(pw);
      int h0 = (int)fh0, w0 = (int)fw0;
      float wh1 = ph - fh0, ww1 = pw - fw0;
      float wh0 = 1.0f - wh1, ww0 = 1.0f - ww1;
      int r0 = h0 - 1, c0 = w0 - 1;    // x coords

      union { unsigned u[4]; half8 v; } Af[2];
#pragma unroll
      for (int sh = 0; sh < 2; ++sh) {
#pragma unroll
        for (int t = 0; t < 4; ++t) {
          float v2[2];
#pragma unroll
          for (int e = 0; e < 2; ++e) {
            int ch = sh * 32 + lq * 8 + 2 * t + e;
            float a00 = (_Float16)gs(xb, ch, r0, c0);
            float a01 = (_Float16)gs(xb, ch, r0, c0 + 1);
            float a10 = (_Float16)gs(xb, ch, r0 + 1, c0);
            float a11 = (_Float16)gs(xb, ch, r0 + 1, c0 + 1);
            v2[e] = (a00 * ww0 + a01 * ww1) * wh0 + (a10 * ww0 + a11 * ww1) * wh1;
          }
          U o; o.h = (h2){(_Float16)v2[0], (_Float16)v2[1]};
          Af[sh].u[t] = o.u;
        }
      }
#pragma unroll
      for (int nt = 0; nt < 4; ++nt) {
        half8 b0f = *(const half8*)&wb[(size_t)(nt * 16 + lm) * 576 + kk * 64 + lq * 8];
        half8 b1f = *(const half8*)&wb[(size_t)(nt * 16 + lm) * 576 + kk * 64 + 32 + lq * 8];
        acc[nt] = __builtin_amdgcn_mfma_f32_16x16x32_f16(Af[0].v, b0f, acc[nt], 0, 0, 0);
        acc[nt] = __builtin_amdgcn_mfma_f32_16x16x32_f16(Af[1].v, b1f, acc[nt], 0, 0, 0);
      }
    }
  }

  // ---- epilogue: D col=lm -> o, row=lq*4+r -> pixel ----
  {
    int px0 = lq * 4;
    int hrow = H0 + 2 * wave + (px0 >> 3);
    int wcol = W0 + (px0 & 7);
#pragma unroll
    for (int nt = 0; nt < 4; ++nt) {
      int o = nt * 16 + lm;
      float bv = bias[o];
      float4 st = make_float4(acc[nt][0] + bv, acc[nt][1] + bv, acc[nt][2] + bv, acc[nt][3] + bv);
      *(float4*)(out + ((size_t)(b * OO + o) * HH + hrow) * WW + wcol) = st;
    }
  }
}

extern "C" void kernel_launch(void* const* d_in, const int* in_sizes, int n_in,
                              void* d_out, int out_size, void* d_ws, size_t ws_size,
                              hipStream_t stream) {
  const float* x        = (const float*)d_in[0];
  const float* weight   = (const float*)d_in[1];
  const float* bias     = (const float*)d_in[2];
  const float* offset_w = (const float*)d_in[3];
  const float* offset_b = (const float*)d_in[4];
  float* out = (float*)d_out;

  _Float16* wb  = (_Float16*)d_ws;         // 64*576 f16
  _Float16* owb = wb + (size_t)OO * 576;   // 32*576 f16

  repackw_kernel<<<(OO * 576 + 32 * 576 + 255) / 256, 256, 0, stream>>>(weight, offset_w, wb, owb);
  fused_deform<<<1024, 256, 0, stream>>>(x, wb, owb, offset_b, bias, out);
}

// Round 10
// 120.201 us; speedup vs baseline: 1.2801x; 1.2801x over previous
//
#include <hip/hip_runtime.h>

#define BB 4
#define CC 64
#define OO 64
#define HH 128
#define WW 128
#define HP 131          // padded rows (0..130 valid)
#define WP 132          // padded row width
#define HW (HH*WW)

#define TH 8            // output tile rows per block
#define TW 8            // output tile cols per block
#define WR 15           // staged window rows
#define WC 15           // staged window cols
#define NWIN (WR*WC)    // 225
#define PXS 36          // LDS dwords per window pixel (32 ch-pairs + 4 pad)

typedef __attribute__((ext_vector_type(8))) short short8;
typedef __attribute__((ext_vector_type(4))) float f32x4;

__device__ __forceinline__ unsigned f2b(float f) {  // RNE float->bf16 bits
  unsigned u = __float_as_uint(f);
  return (u + 0x7fffu + ((u >> 16) & 1u)) >> 16;
}
__device__ __forceinline__ float blo(unsigned r) { return __uint_as_float(r << 16); }
__device__ __forceinline__ float bhi(unsigned r) { return __uint_as_float(r & 0xffff0000u); }
__device__ __forceinline__ unsigned pk2(float a, float b) { return f2b(a) | (f2b(b) << 16); }

__device__ __forceinline__ short8 lerp8(uint4 q00, uint4 q01, uint4 q10, uint4 q11,
                                        float ww0, float ww1, float wh0, float wh1) {
  unsigned c00[4] = {q00.x, q00.y, q00.z, q00.w};
  unsigned c01[4] = {q01.x, q01.y, q01.z, q01.w};
  unsigned c10[4] = {q10.x, q10.y, q10.z, q10.w};
  unsigned c11[4] = {q11.x, q11.y, q11.z, q11.w};
  union { unsigned u[4]; short8 v; } A;
#pragma unroll
  for (int t = 0; t < 4; ++t) {
    float tL = fmaf(blo(c01[t]), ww1, blo(c00[t]) * ww0);
    float bL = fmaf(blo(c11[t]), ww1, blo(c10[t]) * ww0);
    float tH = fmaf(bhi(c01[t]), ww1, bhi(c00[t]) * ww0);
    float bH = fmaf(bhi(c11[t]), ww1, bhi(c10[t]) * ww0);
    A.u[t] = pk2(fmaf(bL, wh1, tL * wh0), fmaf(bH, wh1, tH * wh0));
  }
  return A.v;
}

// ---------------- pad + bf16 + CHANNEL-LAST: xp[b][hp][wp][c2] ----------------
__global__ __launch_bounds__(256) void pad_kernel(const float* __restrict__ x,
                                                  unsigned* __restrict__ xp) {
  int i = blockIdx.x * 256 + threadIdx.x;       // (b,hp,wp,c8)
  if (i >= BB * HP * WP * 8) return;
  int c8 = i & 7;
  int t = i >> 3;
  int wp = t % WP;
  int t2 = t / WP;
  int hp = t2 % HP;
  int b = t2 / HP;
  uint4 v = make_uint4(0, 0, 0, 0);
  if (hp >= 1 && hp <= HH && wp >= 1 && wp <= WW) {
    const float* s = x + (((size_t)(b * CC + c8 * 8)) * HH + (hp - 1)) * WW + (wp - 1);
    v.x = pk2(s[0], s[HW]);
    v.y = pk2(s[2 * HW], s[3 * HW]);
    v.z = pk2(s[4 * HW], s[5 * HW]);
    v.w = pk2(s[6 * HW], s[7 * HW]);
  }
  *(uint4*)(xp + (size_t)t * 32 + c8 * 4) = v;
}

// ---------------- weight repack: MFMA-FRAGMENT ORDER ----------------
// main: tile T=(kk*2+sh)*4+nt (72 tiles); within tile lane L stores 8 bf16:
//   o = nt*16 + (L&15), c = sh*32 + (L>>4)*8 + j  ->  wbf[T*512 + L*8 + j]
// offs: tile T=(kk*2+sh)*2+nt (36 tiles), rows oc>=18 zero.
__global__ __launch_bounds__(256) void repackw_kernel(const float* __restrict__ wt,
                                                      const float* __restrict__ ow,
                                                      ushort* __restrict__ wbf,
                                                      ushort* __restrict__ owbf) {
  int i = blockIdx.x * 256 + threadIdx.x;
  if (i < 72 * 512) {
    int j = i & 7, lane = (i >> 3) & 63, T = i >> 9;
    int nt = T & 3, sh = (T >> 2) & 1, kk = T >> 3;
    int o = nt * 16 + (lane & 15);
    int c = sh * 32 + (lane >> 4) * 8 + j;
    wbf[i] = (ushort)f2b(wt[(o * CC + c) * 9 + kk]);
  } else if (i < 72 * 512 + 36 * 512) {
    int i2 = i - 72 * 512;
    int j = i2 & 7, lane = (i2 >> 3) & 63, T = i2 >> 9;
    int nt = T & 1, sh = (T >> 1) & 1, kk = T >> 2;
    int oc = nt * 16 + (lane & 15);
    int c = sh * 32 + (lane >> 4) * 8 + j;
    owbf[i2] = (oc < 18) ? (ushort)f2b(ow[(oc * CC + c) * 9 + kk]) : (ushort)0;
  }
}

// ---------------- fused: stage window -> offs GEMM -> deform GEMM (phase-split) ----------------
__global__ __launch_bounds__(256, 3) void fused_deform(const unsigned* __restrict__ xp,
                                                       const ushort* __restrict__ wbf,
                                                       const ushort* __restrict__ owbf,
                                                       const float* __restrict__ obias,
                                                       const float* __restrict__ bias,
                                                       float* __restrict__ out) {
  __shared__ __align__(16) unsigned win[NWIN * PXS];   // 32.4 KB
  __shared__ __align__(16) float obuf[64 * 20];        // 5.1 KB

  int tid = threadIdx.x;
  int blk0 = blockIdx.x;
  int xcd = blk0 & 7, i = blk0 >> 3;
  int s = xcd * 8 + (i >> 4);            // slab 0..63 = b*16 + ht
  int b = s >> 4, ht = s & 15, wtile = i & 15;
  int H0 = ht * TH, W0 = wtile * TW;
  int rlo = H0 - 1, clo = W0 - 1;        // window origin, padded coords

  int wave = tid >> 6, lane = tid & 63, lm = lane & 15, lq = lane >> 4;
  const unsigned* xpb = xp + (size_t)b * (HP * WP * 32);

  // ---- stage window (coalesced uint4 from padded bf16 xp) ----
  for (int q = tid; q < NWIN * 8; q += 256) {
    int px = q >> 3, ch = q & 7;
    int r = px / WC, c = px % WC;
    int pr = rlo + r, pc = clo + c;
    uint4 v = make_uint4(0, 0, 0, 0);
    if (pr >= 0 && pr <= HP - 1 && pc >= 0 && pc <= WP - 2)
      v = *(const uint4*)(xpb + ((size_t)pr * WP + pc) * 32 + ch * 4);
    *(uint4*)&win[px * PXS + ch * 4] = v;
  }
  __syncthreads();

  int row = 2 * wave + (lm >> 3);        // tile-local pixel coords for lane lm
  int col = lm & 7;
  int h = H0 + row, w = W0 + col;

  // ---- offs GEMM, phase-split; B-loads coalesced fragment tiles ----
  {
    short8 Ao0[9], Ao1[9];
#pragma unroll
    for (int kk = 0; kk < 9; ++kk) {
      int kh = kk / 3, kw = kk % 3;
      int widx = (row + kh + 1) * WC + (col + kw + 1);
      const unsigned* wp0 = &win[widx * PXS + lq * 4];
      Ao0[kk] = *(const short8*)wp0;
      Ao1[kk] = *(const short8*)(wp0 + 16);
    }
    f32x4 oacc[2];
    oacc[0] = (f32x4)0.0f; oacc[1] = (f32x4)0.0f;
#pragma unroll
    for (int nt = 0; nt < 2; ++nt) {
#pragma unroll
      for (int kk = 0; kk < 9; ++kk) {
        short8 b0 = *(const short8*)&owbf[(size_t)(kk * 4 + nt) * 512 + lane * 8];
        short8 b1 = *(const short8*)&owbf[(size_t)(kk * 4 + 2 + nt) * 512 + lane * 8];
        oacc[nt] = __builtin_amdgcn_mfma_f32_16x16x32_bf16(Ao0[kk], b0, oacc[nt], 0, 0, 0);
        oacc[nt] = __builtin_amdgcn_mfma_f32_16x16x32_bf16(Ao1[kk], b1, oacc[nt], 0, 0, 0);
      }
    }
#pragma unroll
    for (int nt = 0; nt < 2; ++nt) {
      int oc = nt * 16 + lm;
      if (oc < 18) {
        float bv = obias[oc];
        int idx = (oc < 9) ? (oc * 2) : ((oc - 9) * 2 + 1);
#pragma unroll
        for (int r2 = 0; r2 < 4; ++r2)
          obuf[(wave * 16 + lq * 4 + r2) * 20 + idx] = oacc[nt][r2] + bv;
      }
    }
  }
  __syncthreads();

  float orow[20];
  {
    const float* orp = &obuf[(wave * 16 + lm) * 20];
#pragma unroll
    for (int q = 0; q < 5; ++q) *(float4*)&orow[q * 4] = *(const float4*)(orp + q * 4);
  }

  f32x4 acc[4];
#pragma unroll
  for (int nt = 0; nt < 4; ++nt) acc[nt] = (f32x4)0.0f;

  // ---- Phase 0: all 9 taps of all lanes inside the staged window? ----
  bool okall = true;
#pragma unroll
  for (int kk = 0; kk < 9; ++kk) {
    int kh = kk / 3, kw = kk % 3;
    float ph = (((float)kh + orow[kk * 2]) + (float)h) + 1.0f;
    float pw = (((float)kw + orow[kk * 2 + 1]) + (float)w) + 1.0f;
    ph = fminf(fmaxf(ph, 0.0f), 129.0f);
    pw = fminf(fmaxf(pw, 0.0f), 129.0f);
    int h0 = (int)floorf(ph), w0 = (int)floorf(pw);
    int wr0 = h0 - rlo, wc0 = w0 - clo;
    okall &= (wr0 >= 0) & (wr0 <= WR - 2) & (wc0 >= 0) & (wc0 <= WC - 2);
  }

  if (__builtin_amdgcn_ballot_w64(okall) == ~0ull) {
    // ---- Phase 1: branch-free gather+lerp of ALL taps into held A-frags ----
    short8 Af0[9], Af1[9];
#pragma unroll
    for (int kk = 0; kk < 9; ++kk) {
      int kh = kk / 3, kw = kk % 3;
      float ph = (((float)kh + orow[kk * 2]) + (float)h) + 1.0f;
      float pw = (((float)kw + orow[kk * 2 + 1]) + (float)w) + 1.0f;
      ph = fminf(fmaxf(ph, 0.0f), 129.0f);
      pw = fminf(fmaxf(pw, 0.0f), 129.0f);
      float fh0 = floorf(ph), fw0 = floorf(pw);
      int h0 = (int)fh0, w0 = (int)fw0;
      float wh1 = ph - fh0, ww1 = pw - fw0;
      float wh0 = 1.0f - wh1, ww0 = 1.0f - ww1;
      const unsigned* pA = &win[((h0 - rlo) * WC + (w0 - clo)) * PXS + lq * 4];
      uint4 q00a = *(const uint4*)pA;
      uint4 q01a = *(const uint4*)(pA + PXS);
      uint4 q10a = *(const uint4*)(pA + WC * PXS);
      uint4 q11a = *(const uint4*)(pA + WC * PXS + PXS);
      uint4 q00b = *(const uint4*)(pA + 16);
      uint4 q01b = *(const uint4*)(pA + PXS + 16);
      uint4 q10b = *(const uint4*)(pA + WC * PXS + 16);
      uint4 q11b = *(const uint4*)(pA + WC * PXS + PXS + 16);
      Af0[kk] = lerp8(q00a, q01a, q10a, q11a, ww0, ww1, wh0, wh1);
      Af1[kk] = lerp8(q00b, q01b, q10b, q11b, ww0, ww1, wh0, wh1);
    }
    // ---- Phase 2: pure GEMM; B-loads = contiguous lane*16B fragment tiles ----
#pragma unroll
    for (int nt = 0; nt < 4; ++nt) {
#pragma unroll
      for (int kk = 0; kk < 9; ++kk) {
        short8 b0 = *(const short8*)&wbf[(size_t)(kk * 8 + nt) * 512 + lane * 8];
        short8 b1 = *(const short8*)&wbf[(size_t)(kk * 8 + 4 + nt) * 512 + lane * 8];
        acc[nt] = __builtin_amdgcn_mfma_f32_16x16x32_bf16(Af0[kk], b0, acc[nt], 0, 0, 0);
        acc[nt] = __builtin_amdgcn_mfma_f32_16x16x32_bf16(Af1[kk], b1, acc[nt], 0, 0, 0);
      }
    }
  } else {
    // ---- cold exact path (not taken for this data): per-tap global xp gather ----
#pragma unroll 1
    for (int kk = 0; kk < 9; ++kk) {
      int kh = kk / 3, kw = kk % 3;
      float ph = (((float)kh + orow[kk * 2]) + (float)h) + 1.0f;
      float pw = (((float)kw + orow[kk * 2 + 1]) + (float)w) + 1.0f;
      ph = fminf(fmaxf(ph, 0.0f), 129.0f);
      pw = fminf(fmaxf(pw, 0.0f), 129.0f);
      float fh0 = floorf(ph), fw0 = floorf(pw);
      int h0 = (int)fh0, w0 = (int)fw0;
      float wh1 = ph - fh0, ww1 = pw - fw0;
      float wh0 = 1.0f - wh1, ww0 = 1.0f - ww1;
      const unsigned* pG = xpb + ((size_t)h0 * WP + w0) * 32 + lq * 4;
      uint4 q00a = *(const uint4*)pG;
      uint4 q01a = *(const uint4*)(pG + 32);
      uint4 q10a = *(const uint4*)(pG + WP * 32);
      uint4 q11a = *(const uint4*)(pG + WP * 32 + 32);
      uint4 q00b = *(const uint4*)(pG + 16);
      uint4 q01b = *(const uint4*)(pG + 48);
      uint4 q10b = *(const uint4*)(pG + WP * 32 + 16);
      uint4 q11b = *(const uint4*)(pG + WP * 32 + 48);
      short8 A0v = lerp8(q00a, q01a, q10a, q11a, ww0, ww1, wh0, wh1);
      short8 A1v = lerp8(q00b, q01b, q10b, q11b, ww0, ww1, wh0, wh1);
#pragma unroll
      for (int nt = 0; nt < 4; ++nt) {
        short8 b0 = *(const short8*)&wbf[(size_t)(kk * 8 + nt) * 512 + lane * 8];
        short8 b1 = *(const short8*)&wbf[(size_t)(kk * 8 + 4 + nt) * 512 + lane * 8];
        acc[nt] = __builtin_amdgcn_mfma_f32_16x16x32_bf16(A0v, b0, acc[nt], 0, 0, 0);
        acc[nt] = __builtin_amdgcn_mfma_f32_16x16x32_bf16(A1v, b1, acc[nt], 0, 0, 0);
      }
    }
  }

  // ---- epilogue ----
  {
    int px0 = lq * 4;
    int hrow = H0 + 2 * wave + (px0 >> 3);
    int wcol = W0 + (px0 & 7);
#pragma unroll
    for (int nt = 0; nt < 4; ++nt) {
      int o = nt * 16 + lm;
      float bv = bias[o];
      float4 st = make_float4(acc[nt][0] + bv, acc[nt][1] + bv, acc[nt][2] + bv, acc[nt][3] + bv);
      *(float4*)(out + ((size_t)(b * OO + o) * HH + hrow) * WW + wcol) = st;
    }
  }
}

extern "C" void kernel_launch(void* const* d_in, const int* in_sizes, int n_in,
                              void* d_out, int out_size, void* d_ws, size_t ws_size,
                              hipStream_t stream) {
  const float* x        = (const float*)d_in[0];
  const float* weight   = (const float*)d_in[1];
  const float* bias     = (const float*)d_in[2];
  const float* offset_w = (const float*)d_in[3];
  const float* offset_b = (const float*)d_in[4];
  float* out = (float*)d_out;

  unsigned* xp  = (unsigned*)d_ws;                          // 4*131*132*32 uints = 8.85 MB
  ushort* wbf  = (ushort*)(xp + (size_t)BB * HP * WP * 32); // 72*512 ushorts
  ushort* owbf = wbf + (size_t)72 * 512;                    // 36*512 ushorts

  pad_kernel<<<(BB * HP * WP * 8 + 255) / 256, 256, 0, stream>>>(x, xp);
  repackw_kernel<<<(72 * 512 + 36 * 512 + 255) / 256, 256, 0, stream>>>(weight, offset_w, wbf, owbf);
  fused_deform<<<1024, 256, 0, stream>>>(xp, wbf, owbf, offset_b, bias, out);
}